// Round 2
// baseline (3030.989 us; speedup 1.0000x reference)
//
#include <hip/hip_runtime.h>
#include <stdint.h>

// ---- problem constants (B=4, H=W=224, C=192, heads=6, win=7, shift=3) ----
#define MB    50176         // tokens per batch image (224*224)
#define WINB  1024          // windows per batch image (32*32)
#define CDIM  192

__device__ __forceinline__ float wsum(float v){
  #pragma unroll
  for (int m=32;m>=1;m>>=1) v += __shfl_xor(v,m,64);
  return v;
}
__device__ __forceinline__ float wmax(float v){
  #pragma unroll
  for (int m=32;m>=1;m>>=1) v = fmaxf(v,__shfl_xor(v,m,64));
  return v;
}
__device__ __forceinline__ float bfbits2f(uint32_t h){
  union{uint32_t u; float f;} x; x.u = h<<16; return x.f;
}
__device__ __forceinline__ uint16_t f2bfbits(float f){
  union{float ff; uint32_t u;} x; x.ff = f;
  return (uint16_t)((x.u + 0x7FFFu + ((x.u>>16)&1u)) >> 16);
}

// ---------------- LayerNorm -> bf16 (optionally with shifted-window gather)
// one wave (64 lanes) per token; 192 = 3 * 64 channels. Operates on ONE batch
// image (MB tokens); src/dst pre-offset by caller.
template<bool GATHER>
__global__ __launch_bounds__(256) void ln_kernel(
    const float* __restrict__ src, const float* __restrict__ g,
    const float* __restrict__ bt, uint16_t* __restrict__ dst){
  int wid  = (int)((blockIdx.x*256u + threadIdx.x) >> 6);   // token id in dst order
  int lane = threadIdx.x & 63;
  int sidx;
  if (GATHER){
    int widx = wid/49, tpos = wid - widx*49;
    int wh = widx>>5, ww = widx&31;
    int th = tpos/7, tw = tpos - th*7;
    int h = wh*7+th+3; if (h>=224) h-=224;   // xs[h'] = xn[(h'+shift) mod H]
    int w = ww*7+tw+3; if (w>=224) w-=224;
    sidx = h*224 + w;
  } else {
    sidx = wid;
  }
  const float* s = src + (size_t)sidx*CDIM;
  float v0=s[lane], v1=s[lane+64], v2=s[lane+128];
  float mu  = wsum(v0+v1+v2) * (1.f/192.f);
  float var = wsum(v0*v0+v1*v1+v2*v2)*(1.f/192.f) - mu*mu;
  float rs  = rsqrtf(var + 1e-5f);
  uint16_t* d = dst + (size_t)wid*CDIM;
  d[lane]     = f2bfbits((v0-mu)*rs*g[lane]     + bt[lane]);
  d[lane+64]  = f2bfbits((v1-mu)*rs*g[lane+64]  + bt[lane+64]);
  d[lane+128] = f2bfbits((v2-mu)*rs*g[lane+128] + bt[lane+128]);
}

// ---------------- generic tiled GEMM (A bf16, W f32) with fused epilogues ---
enum { EPI_QKV=0, EPI_PROJ=1, EPI_FC1=2, EPI_FC2=3 };

template<int EPI, int K, int NN>
__global__ __launch_bounds__(256) void gemm_kernel(
    const uint16_t* __restrict__ A, const float* __restrict__ W,
    const float* __restrict__ bias, void* __restrict__ outp,
    const float* __restrict__ resid){
  __shared__ float As[16][64];
  __shared__ float Bs[16][64];
  const int tid = threadIdx.x;
  const int tx = tid & 15, ty = tid >> 4;
  const int brow = blockIdx.y*64, bcol = blockIdx.x*64;
  float acc[4][4] = {};
  const int ar = tid>>2, ak = (tid&3)<<2;
  const int bk = tid>>4, bc = (tid&15)<<2;
  for (int k0=0;k0<K;k0+=16){
    uint2 av = *(const uint2*)(A + (size_t)(brow+ar)*K + k0 + ak);
    As[ak+0][ar]=bfbits2f(av.x & 0xFFFFu);
    As[ak+1][ar]=bfbits2f(av.x >> 16);
    As[ak+2][ar]=bfbits2f(av.y & 0xFFFFu);
    As[ak+3][ar]=bfbits2f(av.y >> 16);
    *(float4*)&Bs[bk][bc] = *(const float4*)(W + (size_t)(k0+bk)*NN + bcol + bc);
    __syncthreads();
    #pragma unroll
    for (int kk=0;kk<16;kk++){
      float4 a4 = *(const float4*)&As[kk][ty<<2];
      float4 b4 = *(const float4*)&Bs[kk][tx<<2];
      float ar4[4]={a4.x,a4.y,a4.z,a4.w};
      float br4[4]={b4.x,b4.y,b4.z,b4.w};
      #pragma unroll
      for (int i=0;i<4;i++)
        #pragma unroll
        for (int j=0;j<4;j++)
          acc[i][j] = fmaf(ar4[i], br4[j], acc[i][j]);
    }
    __syncthreads();
  }
  const int c0 = bcol + (tx<<2);
  float bi[4];
  #pragma unroll
  for (int j=0;j<4;j++) bi[j] = bias[c0+j];
  #pragma unroll
  for (int i=0;i<4;i++){
    int r = brow + (ty<<2) + i;
    if constexpr (EPI==EPI_QKV || EPI==EPI_FC1){
      uint32_t o4[4];
      #pragma unroll
      for (int j=0;j<4;j++){
        float v = acc[i][j] + bi[j];
        if constexpr (EPI==EPI_FC1)
          v = 0.5f*v*(1.f + erff(v*0.70710678118654752f));   // exact gelu
        o4[j] = f2bfbits(v);
      }
      uint2 pk = make_uint2(o4[0] | (o4[1]<<16), o4[2] | (o4[3]<<16));
      *(uint2*)((uint16_t*)outp + (size_t)r*NN + c0) = pk;
    } else if constexpr (EPI==EPI_PROJ){
      // window-reverse + roll-back scatter within this batch image,
      // + shortcut residual (original x, pre-offset)
      int widx = r/49, tpos = r - widx*49;
      int wh = widx>>5, ww = widx&31;
      int th = tpos/7, tw = tpos - th*7;
      int h = wh*7+th+3; if (h>=224) h-=224;
      int w = ww*7+tw+3; if (w>=224) w-=224;
      size_t p = ((size_t)h*224 + w)*CDIM + c0;
      float4 rv = *(const float4*)(resid + p);
      float4 ov = make_float4(acc[i][0]+bi[0]+rv.x, acc[i][1]+bi[1]+rv.y,
                              acc[i][2]+bi[2]+rv.z, acc[i][3]+bi[3]+rv.w);
      *(float4*)((float*)outp + p) = ov;
    } else { // EPI_FC2: + residual (x2)
      size_t p = (size_t)r*CDIM + c0;
      float4 rv = *(const float4*)(resid + p);
      float4 ov = make_float4(acc[i][0]+bi[0]+rv.x, acc[i][1]+bi[1]+rv.y,
                              acc[i][2]+bi[2]+rv.z, acc[i][3]+bi[3]+rv.w);
      *(float4*)((float*)outp + p) = ov;
    }
  }
}

// ---------------- windowed attention: one block per (window, head) ---------
// Operates on ONE batch image (WINB windows); qkv/attnout pre-offset.
__global__ __launch_bounds__(256) void attn_kernel(
    const uint16_t* __restrict__ qkv, const float* __restrict__ rpb,
    uint16_t* __restrict__ attnout){
  const int bid = blockIdx.x;
  const int widx = bid/6, hd = bid - widx*6;
  __shared__ float qs[49][33], ks[49][33], vs[49][33];  // +1 pad: no 32-way conflict
  __shared__ float sc[49][52];
  __shared__ int lab[49];
  const int tid = threadIdx.x;

  for (int e=tid; e<49*32; e+=256){
    int i=e>>5, c=e&31;
    size_t base = ((size_t)widx*49 + i)*576 + hd*32 + c;
    qs[i][c] = bfbits2f(qkv[base])     * 0.17677669529663689f; // q * ch^-0.5
    ks[i][c] = bfbits2f(qkv[base+192]);
    vs[i][c] = bfbits2f(qkv[base+384]);
  }
  if (tid < 49){
    int hs  = (widx>>5)*7 + tid/7;     // plain (mask) coordinates
    int ws2 = (widx&31)*7 + (tid%7);
    int rh = hs<217?0:(hs<221?1:2);
    int rw = ws2<217?0:(ws2<221?1:2);
    lab[tid] = rh*3+rw;
  }
  __syncthreads();

  for (int e=tid; e<49*49; e+=256){
    int i=e/49, j=e-i*49;
    float d=0.f;
    #pragma unroll
    for (int c=0;c<32;c++) d = fmaf(qs[i][c], ks[j][c], d);
    int dh = i/7 - j/7, dw = i%7 - j%7;
    d += rpb[((dh+6)*13 + (dw+6))*6 + hd];
    if (lab[i]!=lab[j]) d -= 1e9f;
    sc[i][j]=d;
  }
  __syncthreads();

  const int lane = tid&63, wv = tid>>6;
  for (int r=wv; r<49; r+=4){
    float v = (lane<49)? sc[r][lane] : -3.4e38f;
    float m = wmax(v);
    float p = (lane<49)? __expf(v-m) : 0.f;
    float sm = wsum(p);
    if (lane<49) sc[r][lane] = p/sm;
  }
  __syncthreads();

  for (int e=tid; e<49*32; e+=256){
    int i=e>>5, c=e&31;
    float a=0.f;
    #pragma unroll
    for (int j=0;j<49;j++) a = fmaf(sc[i][j], vs[j][c], a);
    attnout[((size_t)widx*49 + i)*CDIM + hd*32 + c] = f2bfbits(a);
  }
}

// ---------------------------------------------------------------------------
extern "C" void kernel_launch(void* const* d_in, const int* in_sizes, int n_in,
                              void* d_out, int out_size, void* d_ws, size_t ws_size,
                              hipStream_t stream) {
  const float* x       = (const float*)d_in[0];
  const float* n1g     = (const float*)d_in[1];
  const float* n1b     = (const float*)d_in[2];
  const float* qkv_w   = (const float*)d_in[3];
  const float* qkv_b   = (const float*)d_in[4];
  const float* rpb     = (const float*)d_in[5];
  const float* proj_w  = (const float*)d_in[6];
  const float* proj_b  = (const float*)d_in[7];
  const float* n2g     = (const float*)d_in[8];
  const float* n2b     = (const float*)d_in[9];
  const float* fc1_w   = (const float*)d_in[10];
  const float* fc1_b   = (const float*)d_in[11];
  const float* fc2_w   = (const float*)d_in[12];
  const float* fc2_b   = (const float*)d_in[13];
  float* out = (float*)d_out;

  // chunked-by-batch workspace: peak 19.3 MB + 77.1 MB = 96.4 MB
  uint16_t* A  = (uint16_t*)d_ws;                          // MB*192 bf16 (xw/attnout/xn2)
  uint16_t* Bq = (uint16_t*)((char*)d_ws + (size_t)MB*CDIM*2); // MB*768 bf16 (qkv then hid)

  // ---- phase 1: attention path, per batch image ----
  for (int b=0;b<4;b++){
    const float* xb = x   + (size_t)b*MB*CDIM;
    float*      ob  = out + (size_t)b*MB*CDIM;
    // 1) LN1 + roll + window partition -> A (bf16)
    ln_kernel<true><<<MB/4, 256, 0, stream>>>(xb, n1g, n1b, A);
    // 2) qkv projection -> Bq (bf16)
    gemm_kernel<EPI_QKV, 192, 576>
        <<<dim3(9, MB/64), 256, 0, stream>>>(A, qkv_w, qkv_b, (void*)Bq, nullptr);
    // 3) windowed attention -> A (bf16)
    attn_kernel<<<WINB*6, 256, 0, stream>>>(Bq, rpb, A);
    // 4) proj + window-reverse + roll-back + shortcut residual -> out (= x2)
    gemm_kernel<EPI_PROJ, 192, 192>
        <<<dim3(3, MB/64), 256, 0, stream>>>(A, proj_w, proj_b, (void*)ob, xb);
  }
  // ---- phase 2: MLP path, per batch image ----
  for (int b=0;b<4;b++){
    float* ob = out + (size_t)b*MB*CDIM;
    // 5) LN2 -> A (bf16)
    ln_kernel<false><<<MB/4, 256, 0, stream>>>(ob, n2g, n2b, A);
    // 6) fc1 + exact gelu -> Bq (bf16)
    gemm_kernel<EPI_FC1, 192, 768>
        <<<dim3(12, MB/64), 256, 0, stream>>>(A, fc1_w, fc1_b, (void*)Bq, nullptr);
    // 7) fc2 + residual(x2) -> out
    gemm_kernel<EPI_FC2, 768, 192>
        <<<dim3(3, MB/64), 256, 0, stream>>>(Bq, fc2_w, fc2_b, (void*)ob, ob);
  }
}

// Round 3
// 1231.077 us; speedup vs baseline: 2.4621x; 2.4621x over previous
//
#include <hip/hip_runtime.h>
#include <stdint.h>

// ---- problem constants (B=4, H=W=224, C=192, heads=6, win=7, shift=3) ----
#define MB    50176         // tokens per batch image (224*224)
#define WINB  1024          // windows per batch image (32*32)
#define CDIM  192

typedef __attribute__((ext_vector_type(8))) short bf16x8;   // MFMA A/B frag (4 VGPR)
typedef __attribute__((ext_vector_type(4))) float f32x4;    // MFMA C/D frag

__device__ __forceinline__ float wsum(float v){
  #pragma unroll
  for (int m=32;m>=1;m>>=1) v += __shfl_xor(v,m,64);
  return v;
}
__device__ __forceinline__ float wmax(float v){
  #pragma unroll
  for (int m=32;m>=1;m>>=1) v = fmaxf(v,__shfl_xor(v,m,64));
  return v;
}
__device__ __forceinline__ float bfbits2f(uint32_t h){
  union{uint32_t u; float f;} x; x.u = h<<16; return x.f;
}
__device__ __forceinline__ uint16_t f2bfbits(float f){
  union{float ff; uint32_t u;} x; x.ff = f;
  return (uint16_t)((x.u + 0x7FFFu + ((x.u>>16)&1u)) >> 16);
}
__device__ __forceinline__ void gload16(const void* g, void* l){
  __builtin_amdgcn_global_load_lds(
      (const __attribute__((address_space(1))) uint32_t*)g,
      (__attribute__((address_space(3))) uint32_t*)l, 16, 0, 0);
}

// ---------------- weight convert: f32 [K][N] -> bf16 [N][K] ----------------
__global__ __launch_bounds__(256) void wconv_kernel(
    const float* __restrict__ W, uint16_t* __restrict__ WT, int K, int N){
  int idx = blockIdx.x*256 + threadIdx.x;
  if (idx >= K*N) return;
  int k = idx / N, n = idx - k*N;
  WT[(size_t)n*K + k] = f2bfbits(W[idx]);
}

// ---------------- LayerNorm -> bf16 (optionally shifted-window gather) -----
template<bool GATHER>
__global__ __launch_bounds__(256) void ln_kernel(
    const float* __restrict__ src, const float* __restrict__ g,
    const float* __restrict__ bt, uint16_t* __restrict__ dst){
  int wid  = (int)((blockIdx.x*256u + threadIdx.x) >> 6);
  int lane = threadIdx.x & 63;
  int sidx;
  if (GATHER){
    int widx = wid/49, tpos = wid - widx*49;
    int wh = widx>>5, ww = widx&31;
    int th = tpos/7, tw = tpos - th*7;
    int h = wh*7+th+3; if (h>=224) h-=224;
    int w = ww*7+tw+3; if (w>=224) w-=224;
    sidx = h*224 + w;
  } else {
    sidx = wid;
  }
  const float* s = src + (size_t)sidx*CDIM;
  float v0=s[lane], v1=s[lane+64], v2=s[lane+128];
  float mu  = wsum(v0+v1+v2) * (1.f/192.f);
  float var = wsum(v0*v0+v1*v1+v2*v2)*(1.f/192.f) - mu*mu;
  float rs  = rsqrtf(var + 1e-5f);
  uint16_t* d = dst + (size_t)wid*CDIM;
  d[lane]     = f2bfbits((v0-mu)*rs*g[lane]     + bt[lane]);
  d[lane+64]  = f2bfbits((v1-mu)*rs*g[lane+64]  + bt[lane+64]);
  d[lane+128] = f2bfbits((v2-mu)*rs*g[lane+128] + bt[lane+128]);
}

// ---------------- MFMA GEMM: A bf16 [M][K], WT bf16 [N][K], 128x64 tile ----
// 256 threads = 4 waves (2x2), wave tile 64x32, mfma_f32_16x16x32_bf16.
// LDS content XOR-swizzled (granule ^= row&7) via pre-swizzled global source
// on the gload_lds side and swizzled address on the ds_read side (rule #21).
enum { EPI_QKV=0, EPI_PROJ=1, EPI_FC1=2, EPI_FC2=3 };

template<int EPI, int K, int NN>
__global__ __launch_bounds__(256) void mgemm(
    const uint16_t* __restrict__ A, const uint16_t* __restrict__ WT,
    const float* __restrict__ bias, void* __restrict__ outp,
    const float* __restrict__ resid){
  __shared__ __attribute__((aligned(16))) char As[128*128]; // [128 rows][64 k] bf16
  __shared__ __attribute__((aligned(16))) char Bs[64*128];  // [64 n-rows][64 k] bf16
  const int tid  = threadIdx.x;
  const int lane = tid & 63;
  const int wid  = tid >> 6;
  const int brow = blockIdx.y * 128;
  const int bcol = blockIdx.x * 64;

  f32x4 acc[4][2];
  #pragma unroll
  for (int m=0;m<4;m++)
    #pragma unroll
    for (int n=0;n<2;n++) acc[m][n] = (f32x4){0.f,0.f,0.f,0.f};

  // staging: chunk = 8 rows x 8 granules(16B); lane -> (row=lane>>3, g=lane&7)
  const int srow = lane >> 3;
  const int sg   = (lane & 7) ^ srow;         // pre-swizzled source granule
  const int wm = wid >> 1, wn = wid & 1;
  const int lrow16 = lane & 15, lkh = lane >> 4;

  for (int k0 = 0; k0 < K; k0 += 64){
    #pragma unroll
    for (int c = 0; c < 4; c++){               // A tile: 16 chunks, 4/wave
      int ch = wid*4 + c;
      const uint16_t* g = A + (size_t)(brow + ch*8 + srow)*K + k0 + sg*8;
      gload16(g, As + ch*1024);
    }
    #pragma unroll
    for (int c = 0; c < 2; c++){               // B tile: 8 chunks, 2/wave
      int ch = wid*2 + c;
      const uint16_t* g = WT + (size_t)(bcol + ch*8 + srow)*K + k0 + sg*8;
      gload16(g, Bs + ch*1024);
    }
    __syncthreads();   // drains vmcnt before any wave reads LDS

    bf16x8 af[4][2], bfr[2][2];
    #pragma unroll
    for (int m=0;m<4;m++)
      #pragma unroll
      for (int ks=0;ks<2;ks++){
        int arow = wm*64 + m*16 + lrow16;
        int g0 = ks*4 + lkh;
        af[m][ks] = *(const bf16x8*)(As + arow*128 + ((g0 ^ (arow&7))<<4));
      }
    #pragma unroll
    for (int n=0;n<2;n++)
      #pragma unroll
      for (int ks=0;ks<2;ks++){
        int brn = wn*32 + n*16 + lrow16;
        int g0 = ks*4 + lkh;
        bfr[n][ks] = *(const bf16x8*)(Bs + brn*128 + ((g0 ^ (brn&7))<<4));
      }
    #pragma unroll
    for (int m=0;m<4;m++)
      #pragma unroll
      for (int n=0;n<2;n++)
        #pragma unroll
        for (int ks=0;ks<2;ks++)
          acc[m][n] = __builtin_amdgcn_mfma_f32_16x16x32_bf16(
              af[m][ks], bfr[n][ks], acc[m][n], 0, 0, 0);
    __syncthreads();   // all reads done before next-iter staging overwrites
  }

  // epilogue: C[row][col], row=(lane>>4)*4+j, col=lane&15 within 16x16 frag
  float bi[2];
  #pragma unroll
  for (int n=0;n<2;n++) bi[n] = bias[bcol + wn*32 + n*16 + lrow16];
  #pragma unroll
  for (int m=0;m<4;m++){
    #pragma unroll
    for (int j=0;j<4;j++){
      int r = brow + wm*64 + m*16 + lkh*4 + j;
      if constexpr (EPI==EPI_QKV || EPI==EPI_FC1){
        #pragma unroll
        for (int n=0;n<2;n++){
          float v = acc[m][n][j] + bi[n];
          if constexpr (EPI==EPI_FC1)
            v = 0.5f*v*(1.f + erff(v*0.70710678118654752f));  // exact gelu
          ((uint16_t*)outp)[(size_t)r*NN + bcol + wn*32 + n*16 + lrow16] = f2bfbits(v);
        }
      } else if constexpr (EPI==EPI_PROJ){
        // window-reverse + roll-back scatter + shortcut residual
        int widx = r/49, tpos = r - widx*49;
        int wh = widx>>5, ww = widx&31;
        int th = tpos/7, tw = tpos - th*7;
        int h = wh*7+th+3; if (h>=224) h-=224;
        int w = ww*7+tw+3; if (w>=224) w-=224;
        size_t pr = ((size_t)h*224 + w)*CDIM;
        #pragma unroll
        for (int n=0;n<2;n++){
          size_t p = pr + bcol + wn*32 + n*16 + lrow16;
          ((float*)outp)[p] = acc[m][n][j] + bi[n] + resid[p];
        }
      } else { // EPI_FC2: + residual (x2)
        size_t pr = (size_t)r*NN;
        #pragma unroll
        for (int n=0;n<2;n++){
          size_t p = pr + bcol + wn*32 + n*16 + lrow16;
          ((float*)outp)[p] = acc[m][n][j] + bi[n] + resid[p];
        }
      }
    }
  }
}

// ---------------- windowed attention: one block per (window, head) ---------
__global__ __launch_bounds__(256) void attn_kernel(
    const uint16_t* __restrict__ qkv, const float* __restrict__ rpb,
    uint16_t* __restrict__ attnout){
  const int bid = blockIdx.x;
  const int widx = bid/6, hd = bid - widx*6;
  __shared__ float qs[49][33], ks[49][33], vs[49][33];
  __shared__ float sc[49][52];
  __shared__ int lab[49];
  const int tid = threadIdx.x;

  for (int e=tid; e<49*32; e+=256){
    int i=e>>5, c=e&31;
    size_t base = ((size_t)widx*49 + i)*576 + hd*32 + c;
    qs[i][c] = bfbits2f(qkv[base])     * 0.17677669529663689f;
    ks[i][c] = bfbits2f(qkv[base+192]);
    vs[i][c] = bfbits2f(qkv[base+384]);
  }
  if (tid < 49){
    int hs  = (widx>>5)*7 + tid/7;
    int ws2 = (widx&31)*7 + (tid%7);
    int rh = hs<217?0:(hs<221?1:2);
    int rw = ws2<217?0:(ws2<221?1:2);
    lab[tid] = rh*3+rw;
  }
  __syncthreads();

  for (int e=tid; e<49*49; e+=256){
    int i=e/49, j=e-i*49;
    float d=0.f;
    #pragma unroll
    for (int c=0;c<32;c++) d = fmaf(qs[i][c], ks[j][c], d);
    int dh = i/7 - j/7, dw = i%7 - j%7;
    d += rpb[((dh+6)*13 + (dw+6))*6 + hd];
    if (lab[i]!=lab[j]) d -= 1e9f;
    sc[i][j]=d;
  }
  __syncthreads();

  const int lane = tid&63, wv = tid>>6;
  for (int r=wv; r<49; r+=4){
    float v = (lane<49)? sc[r][lane] : -3.4e38f;
    float m = wmax(v);
    float p = (lane<49)? __expf(v-m) : 0.f;
    float sm = wsum(p);
    if (lane<49) sc[r][lane] = p/sm;
  }
  __syncthreads();

  for (int e=tid; e<49*32; e+=256){
    int i=e>>5, c=e&31;
    float a=0.f;
    #pragma unroll
    for (int j=0;j<49;j++) a = fmaf(sc[i][j], vs[j][c], a);
    attnout[((size_t)widx*49 + i)*CDIM + hd*32 + c] = f2bfbits(a);
  }
}

// ---------------------------------------------------------------------------
extern "C" void kernel_launch(void* const* d_in, const int* in_sizes, int n_in,
                              void* d_out, int out_size, void* d_ws, size_t ws_size,
                              hipStream_t stream) {
  const float* x       = (const float*)d_in[0];
  const float* n1g     = (const float*)d_in[1];
  const float* n1b     = (const float*)d_in[2];
  const float* qkv_w   = (const float*)d_in[3];
  const float* qkv_b   = (const float*)d_in[4];
  const float* rpb     = (const float*)d_in[5];
  const float* proj_w  = (const float*)d_in[6];
  const float* proj_b  = (const float*)d_in[7];
  const float* n2g     = (const float*)d_in[8];
  const float* n2b     = (const float*)d_in[9];
  const float* fc1_w   = (const float*)d_in[10];
  const float* fc1_b   = (const float*)d_in[11];
  const float* fc2_w   = (const float*)d_in[12];
  const float* fc2_b   = (const float*)d_in[13];
  float* out = (float*)d_out;

  // workspace: A 19.27MB | Bq 77.07MB | bf16-transposed weights 0.88MB = 97.2MB
  char* ws = (char*)d_ws;
  uint16_t* Abuf = (uint16_t*)ws;
  uint16_t* Bq   = (uint16_t*)(ws + (size_t)MB*CDIM*2);
  char*     wbase = ws + (size_t)MB*CDIM*2 + (size_t)MB*768*2;
  uint16_t* qkvW = (uint16_t*)wbase;                      // [576][192]
  uint16_t* prjW = (uint16_t*)(wbase + 221184);           // [192][192]
  uint16_t* fc1W = (uint16_t*)(wbase + 221184 + 73728);   // [768][192]
  uint16_t* fc2W = (uint16_t*)(wbase + 221184 + 73728 + 294912); // [192][768]

  // 0) weight convert + transpose (f32 KxN -> bf16 NxK)
  wconv_kernel<<<(192*576+255)/256, 256, 0, stream>>>(qkv_w,  qkvW, 192, 576);
  wconv_kernel<<<(192*192+255)/256, 256, 0, stream>>>(proj_w, prjW, 192, 192);
  wconv_kernel<<<(192*768+255)/256, 256, 0, stream>>>(fc1_w,  fc1W, 192, 768);
  wconv_kernel<<<(768*192+255)/256, 256, 0, stream>>>(fc2_w,  fc2W, 768, 192);

  // ---- phase 1: attention path, per batch image ----
  for (int b=0;b<4;b++){
    const float* xb = x   + (size_t)b*MB*CDIM;
    float*      ob  = out + (size_t)b*MB*CDIM;
    ln_kernel<true><<<MB/4, 256, 0, stream>>>(xb, n1g, n1b, Abuf);
    mgemm<EPI_QKV, 192, 576>
        <<<dim3(9, MB/128), 256, 0, stream>>>(Abuf, qkvW, qkv_b, (void*)Bq, nullptr);
    attn_kernel<<<WINB*6, 256, 0, stream>>>(Bq, rpb, Abuf);
    mgemm<EPI_PROJ, 192, 192>
        <<<dim3(3, MB/128), 256, 0, stream>>>(Abuf, prjW, proj_b, (void*)ob, xb);
  }
  // ---- phase 2: MLP path, per batch image ----
  for (int b=0;b<4;b++){
    float* ob = out + (size_t)b*MB*CDIM;
    ln_kernel<false><<<MB/4, 256, 0, stream>>>(ob, n2g, n2b, Abuf);
    mgemm<EPI_FC1, 192, 768>
        <<<dim3(12, MB/128), 256, 0, stream>>>(Abuf, fc1W, fc1_b, (void*)Bq, nullptr);
    mgemm<EPI_FC2, 768, 192>
        <<<dim3(3, MB/128), 256, 0, stream>>>(Bq, fc2W, fc2_b, (void*)ob, ob);
  }
}

// Round 4
// 834.976 us; speedup vs baseline: 3.6300x; 1.4744x over previous
//
#include <hip/hip_runtime.h>
#include <stdint.h>

// ---- problem constants (B=4, H=W=224, C=192, heads=6, win=7, shift=3) ----
#define MB    50176         // tokens per batch image (224*224)
#define WINB  1024          // windows per batch image (32*32)
#define CDIM  192

typedef __attribute__((ext_vector_type(8))) short bf16x8;   // MFMA A/B frag (4 VGPR)
typedef __attribute__((ext_vector_type(4))) float f32x4;    // MFMA C/D frag

__device__ __forceinline__ float wsum(float v){
  #pragma unroll
  for (int m=32;m>=1;m>>=1) v += __shfl_xor(v,m,64);
  return v;
}
__device__ __forceinline__ float bfbits2f(uint32_t h){
  union{uint32_t u; float f;} x; x.u = h<<16; return x.f;
}
__device__ __forceinline__ uint16_t f2bfbits(float f){
  union{float ff; uint32_t u;} x; x.ff = f;
  return (uint16_t)((x.u + 0x7FFFu + ((x.u>>16)&1u)) >> 16);
}
__device__ __forceinline__ void gload16(const void* g, void* l){
  __builtin_amdgcn_global_load_lds(
      (const __attribute__((address_space(1))) uint32_t*)g,
      (__attribute__((address_space(3))) uint32_t*)l, 16, 0, 0);
}

// ---------------- weight convert: f32 [K][N] -> bf16 [N][K] ----------------
__global__ __launch_bounds__(256) void wconv_kernel(
    const float* __restrict__ W, uint16_t* __restrict__ WT, int K, int N){
  int idx = blockIdx.x*256 + threadIdx.x;
  if (idx >= K*N) return;
  int k = idx / N, n = idx - k*N;
  WT[(size_t)n*K + k] = f2bfbits(W[idx]);
}

// ---------------- combined bias+mask table: [4 cls][6 hd][64][64] f32 ------
__global__ __launch_bounds__(256) void btbl_kernel(
    const float* __restrict__ rpb, float* __restrict__ tbl){
  int idx = blockIdx.x*256 + threadIdx.x;
  if (idx >= 4*6*64*64) return;
  int j = idx & 63, i = (idx>>6) & 63;
  int hd = (idx>>12) % 6, cls = idx >> 12; cls /= 6;
  float v = -1e9f;
  if (i < 49 && j < 49){
    int dh = i/7 - j/7, dw = i%7 - j%7;
    v = rpb[((dh+6)*13 + (dw+6))*6 + hd];
    int cH = cls>>1, cW = cls&1;
    int li = (cH ? (i/7 < 4 ? 1 : 2) : 0)*3 + (cW ? (i%7 < 4 ? 1 : 2) : 0);
    int lj = (cH ? (j/7 < 4 ? 1 : 2) : 0)*3 + (cW ? (j%7 < 4 ? 1 : 2) : 0);
    if (li != lj) v = -1e9f;
  }
  tbl[idx] = v;
}

// ---------------- LayerNorm -> bf16 (optionally shifted-window gather) -----
template<bool GATHER>
__global__ __launch_bounds__(256) void ln_kernel(
    const float* __restrict__ src, const float* __restrict__ g,
    const float* __restrict__ bt, uint16_t* __restrict__ dst){
  int wid  = (int)((blockIdx.x*256u + threadIdx.x) >> 6);
  int lane = threadIdx.x & 63;
  int sidx;
  if (GATHER){
    int widx = wid/49, tpos = wid - widx*49;
    int wh = widx>>5, ww = widx&31;
    int th = tpos/7, tw = tpos - th*7;
    int h = wh*7+th+3; if (h>=224) h-=224;
    int w = ww*7+tw+3; if (w>=224) w-=224;
    sidx = h*224 + w;
  } else {
    sidx = wid;
  }
  const float* s = src + (size_t)sidx*CDIM;
  float v0=s[lane], v1=s[lane+64], v2=s[lane+128];
  float mu  = wsum(v0+v1+v2) * (1.f/192.f);
  float var = wsum(v0*v0+v1*v1+v2*v2)*(1.f/192.f) - mu*mu;
  float rs  = rsqrtf(var + 1e-5f);
  uint16_t* d = dst + (size_t)wid*CDIM;
  d[lane]     = f2bfbits((v0-mu)*rs*g[lane]     + bt[lane]);
  d[lane+64]  = f2bfbits((v1-mu)*rs*g[lane+64]  + bt[lane+64]);
  d[lane+128] = f2bfbits((v2-mu)*rs*g[lane+128] + bt[lane+128]);
}

// ---------------- MFMA GEMM: A bf16 [M][K], WT bf16 [N][K], 128x64 tile ----
enum { EPI_QKV=0, EPI_PROJ=1, EPI_FC1=2, EPI_FC2=3 };

template<int EPI, int K, int NN>
__global__ __launch_bounds__(256) void mgemm(
    const uint16_t* __restrict__ A, const uint16_t* __restrict__ WT,
    const float* __restrict__ bias, void* __restrict__ outp,
    const float* __restrict__ resid){
  __shared__ __attribute__((aligned(16))) char As[128*128];
  __shared__ __attribute__((aligned(16))) char Bs[64*128];
  const int tid  = threadIdx.x;
  const int lane = tid & 63;
  const int wid  = tid >> 6;
  const int brow = blockIdx.y * 128;
  const int bcol = blockIdx.x * 64;

  f32x4 acc[4][2];
  #pragma unroll
  for (int m=0;m<4;m++)
    #pragma unroll
    for (int n=0;n<2;n++) acc[m][n] = (f32x4){0.f,0.f,0.f,0.f};

  const int srow = lane >> 3;
  const int sg   = (lane & 7) ^ srow;
  const int wm = wid >> 1, wn = wid & 1;
  const int lrow16 = lane & 15, lkh = lane >> 4;

  for (int k0 = 0; k0 < K; k0 += 64){
    #pragma unroll
    for (int c = 0; c < 4; c++){
      int ch = wid*4 + c;
      const uint16_t* g = A + (size_t)(brow + ch*8 + srow)*K + k0 + sg*8;
      gload16(g, As + ch*1024);
    }
    #pragma unroll
    for (int c = 0; c < 2; c++){
      int ch = wid*2 + c;
      const uint16_t* g = WT + (size_t)(bcol + ch*8 + srow)*K + k0 + sg*8;
      gload16(g, Bs + ch*1024);
    }
    __syncthreads();

    bf16x8 af[4][2], bfr[2][2];
    #pragma unroll
    for (int m=0;m<4;m++)
      #pragma unroll
      for (int ks=0;ks<2;ks++){
        int arow = wm*64 + m*16 + lrow16;
        int g0 = ks*4 + lkh;
        af[m][ks] = *(const bf16x8*)(As + arow*128 + ((g0 ^ (arow&7))<<4));
      }
    #pragma unroll
    for (int n=0;n<2;n++)
      #pragma unroll
      for (int ks=0;ks<2;ks++){
        int brn = wn*32 + n*16 + lrow16;
        int g0 = ks*4 + lkh;
        bfr[n][ks] = *(const bf16x8*)(Bs + brn*128 + ((g0 ^ (brn&7))<<4));
      }
    #pragma unroll
    for (int m=0;m<4;m++)
      #pragma unroll
      for (int n=0;n<2;n++)
        #pragma unroll
        for (int ks=0;ks<2;ks++)
          acc[m][n] = __builtin_amdgcn_mfma_f32_16x16x32_bf16(
              af[m][ks], bfr[n][ks], acc[m][n], 0, 0, 0);
    __syncthreads();
  }

  float bi[2];
  #pragma unroll
  for (int n=0;n<2;n++) bi[n] = bias[bcol + wn*32 + n*16 + lrow16];
  #pragma unroll
  for (int m=0;m<4;m++){
    #pragma unroll
    for (int j=0;j<4;j++){
      int r = brow + wm*64 + m*16 + lkh*4 + j;
      if constexpr (EPI==EPI_QKV || EPI==EPI_FC1){
        #pragma unroll
        for (int n=0;n<2;n++){
          float v = acc[m][n][j] + bi[n];
          if constexpr (EPI==EPI_FC1)
            v = 0.5f*v*(1.f + erff(v*0.70710678118654752f));
          ((uint16_t*)outp)[(size_t)r*NN + bcol + wn*32 + n*16 + lrow16] = f2bfbits(v);
        }
      } else if constexpr (EPI==EPI_PROJ){
        int widx = r/49, tpos = r - widx*49;
        int wh = widx>>5, ww = widx&31;
        int th = tpos/7, tw = tpos - th*7;
        int h = wh*7+th+3; if (h>=224) h-=224;
        int w = ww*7+tw+3; if (w>=224) w-=224;
        size_t pr = ((size_t)h*224 + w)*CDIM;
        #pragma unroll
        for (int n=0;n<2;n++){
          size_t p = pr + bcol + wn*32 + n*16 + lrow16;
          ((float*)outp)[p] = acc[m][n][j] + bi[n] + resid[p];
        }
      } else {
        size_t pr = (size_t)r*NN;
        #pragma unroll
        for (int n=0;n<2;n++){
          size_t p = pr + bcol + wn*32 + n*16 + lrow16;
          ((float*)outp)[p] = acc[m][n][j] + bi[n] + resid[p];
        }
      }
    }
  }
}

// ---------------- MFMA windowed attention: one WAVE per (window, head) -----
// swapped QK^T: acc = mfma(K,Q) -> lane holds S[i=lane&15][j]; in-register
// softmax (16 local + shfl 16/32); P->LDS roundtrip to A-frag; V^T in LDS.
__global__ __launch_bounds__(64) void attn_kernel(
    const uint16_t* __restrict__ qkv, const float* __restrict__ btbl,
    uint16_t* __restrict__ attnout){
  const int bid  = blockIdx.x;
  const int widx = bid/6, hd = bid - widx*6;
  const int lane = threadIdx.x;
  const int r16 = lane & 15, t4 = lane >> 4;
  __shared__ uint16_t Vt[32][72];       // V^T, stride 144B (9 granules: 2-way free)
  __shared__ uint16_t Pl[4][16][72];    // P rows per i-tile

  // zero V^T padding j in [48,64) (avoid 0*inf from stale LDS)
  #pragma unroll
  for (int e=lane; e<32*16; e+=64){ Vt[e>>4][48 + (e&15)] = 0; }
  // stage V^T: read V rows coalesced (16B), scatter ds_write transposed
  for (int ch = lane; ch < 196; ch += 64){
    int j = ch >> 2, c0 = (ch&3)*8;
    const uint16_t* src = qkv + ((size_t)widx*49 + j)*576 + hd*32 + 384 + c0;
    uint4 v = *(const uint4*)src;
    uint32_t u[4] = {v.x, v.y, v.z, v.w};
    #pragma unroll
    for (int q=0;q<8;q++) Vt[c0+q][j] = (uint16_t)(u[q>>1] >> ((q&1)*16));
  }

  // QK^T: acc[jt][it] = S[i = it*16+r16][j = jt*16+t4*4+r]
  bf16x8 kf[4], qf[4];
  #pragma unroll
  for (int jt=0;jt<4;jt++)
    kf[jt] = *(const bf16x8*)(qkv + ((size_t)widx*49 + jt*16 + r16)*576 + hd*32 + 192 + t4*8);
  #pragma unroll
  for (int it=0;it<4;it++)
    qf[it] = *(const bf16x8*)(qkv + ((size_t)widx*49 + it*16 + r16)*576 + hd*32 + t4*8);
  f32x4 acc[4][4];
  #pragma unroll
  for (int jt=0;jt<4;jt++)
    #pragma unroll
    for (int it=0;it<4;it++){
      acc[jt][it] = (f32x4){0.f,0.f,0.f,0.f};
      acc[jt][it] = __builtin_amdgcn_mfma_f32_16x16x32_bf16(kf[jt], qf[it], acc[jt][it], 0,0,0);
    }

  // bias+mask+scale, softmax per i, pack P -> Pl
  const int wh = widx>>5, ww = widx&31;
  const int cls = ((wh==31)<<1) | (ww==31);
  const float* tb = btbl + ((size_t)(cls*6 + hd) << 12);   // [64][64]
  const float scale = 0.17677669529663689f;
  #pragma unroll
  for (int it=0;it<4;it++){
    int i = it*16 + r16;
    float s[4][4];
    float m = -3.4e38f;
    #pragma unroll
    for (int jt=0;jt<4;jt++){
      float4 bv = *(const float4*)(tb + i*64 + jt*16 + t4*4);
      float bb[4] = {bv.x, bv.y, bv.z, bv.w};
      #pragma unroll
      for (int r=0;r<4;r++){
        s[jt][r] = acc[jt][it][r]*scale + bb[r];
        m = fmaxf(m, s[jt][r]);
      }
    }
    m = fmaxf(m, __shfl_xor(m, 16, 64));
    m = fmaxf(m, __shfl_xor(m, 32, 64));
    float sum = 0.f;
    #pragma unroll
    for (int jt=0;jt<4;jt++)
      #pragma unroll
      for (int r=0;r<4;r++){
        s[jt][r] = __expf(s[jt][r] - m);
        sum += s[jt][r];
      }
    sum += __shfl_xor(sum, 16, 64);
    sum += __shfl_xor(sum, 32, 64);
    float inv = 1.f / sum;
    #pragma unroll
    for (int jt=0;jt<4;jt++){
      uint32_t lo = (uint32_t)f2bfbits(s[jt][0]*inv) | ((uint32_t)f2bfbits(s[jt][1]*inv) << 16);
      uint32_t hi = (uint32_t)f2bfbits(s[jt][2]*inv) | ((uint32_t)f2bfbits(s[jt][3]*inv) << 16);
      *(uint2*)&Pl[it][r16][jt*16 + t4*4] = make_uint2(lo, hi);
    }
  }
  __syncthreads();

  // PV: O[i][c] ; A-frag = P rows from Pl, B-frag = V^T rows from Vt
  bf16x8 bv[2][2];
  #pragma unroll
  for (int ct=0;ct<2;ct++)
    #pragma unroll
    for (int ks=0;ks<2;ks++)
      bv[ct][ks] = *(const bf16x8*)&Vt[ct*16 + r16][ks*32 + t4*8];
  #pragma unroll
  for (int it=0;it<4;it++){
    f32x4 o[2];
    o[0] = (f32x4){0.f,0.f,0.f,0.f};
    o[1] = (f32x4){0.f,0.f,0.f,0.f};
    #pragma unroll
    for (int ks=0;ks<2;ks++){
      bf16x8 pa = *(const bf16x8*)&Pl[it][r16][ks*32 + t4*8];
      #pragma unroll
      for (int ct=0;ct<2;ct++)
        o[ct] = __builtin_amdgcn_mfma_f32_16x16x32_bf16(pa, bv[ct][ks], o[ct], 0,0,0);
    }
    #pragma unroll
    for (int r=0;r<4;r++){
      int i = it*16 + t4*4 + r;
      if (i < 49){
        size_t base = ((size_t)widx*49 + i)*CDIM + hd*32;
        attnout[base + r16]      = f2bfbits(o[0][r]);
        attnout[base + 16 + r16] = f2bfbits(o[1][r]);
      }
    }
  }
}

// ---------------------------------------------------------------------------
extern "C" void kernel_launch(void* const* d_in, const int* in_sizes, int n_in,
                              void* d_out, int out_size, void* d_ws, size_t ws_size,
                              hipStream_t stream) {
  const float* x       = (const float*)d_in[0];
  const float* n1g     = (const float*)d_in[1];
  const float* n1b     = (const float*)d_in[2];
  const float* qkv_w   = (const float*)d_in[3];
  const float* qkv_b   = (const float*)d_in[4];
  const float* rpb     = (const float*)d_in[5];
  const float* proj_w  = (const float*)d_in[6];
  const float* proj_b  = (const float*)d_in[7];
  const float* n2g     = (const float*)d_in[8];
  const float* n2b     = (const float*)d_in[9];
  const float* fc1_w   = (const float*)d_in[10];
  const float* fc1_b   = (const float*)d_in[11];
  const float* fc2_w   = (const float*)d_in[12];
  const float* fc2_b   = (const float*)d_in[13];
  float* out = (float*)d_out;

  // workspace: A 19.27MB | Bq 77.07MB | weights 0.88MB | btbl 0.39MB = 97.6MB
  char* ws = (char*)d_ws;
  uint16_t* Abuf = (uint16_t*)ws;
  uint16_t* Bq   = (uint16_t*)(ws + (size_t)MB*CDIM*2);
  char*     wbase = ws + (size_t)MB*CDIM*2 + (size_t)MB*768*2;
  uint16_t* qkvW = (uint16_t*)wbase;                      // [576][192]
  uint16_t* prjW = (uint16_t*)(wbase + 221184);           // [192][192]
  uint16_t* fc1W = (uint16_t*)(wbase + 221184 + 73728);   // [768][192]
  uint16_t* fc2W = (uint16_t*)(wbase + 221184 + 73728 + 294912); // [192][768]
  float*    btbl = (float*)(wbase + 221184 + 73728 + 294912 + 294912);

  wconv_kernel<<<(192*576+255)/256, 256, 0, stream>>>(qkv_w,  qkvW, 192, 576);
  wconv_kernel<<<(192*192+255)/256, 256, 0, stream>>>(proj_w, prjW, 192, 192);
  wconv_kernel<<<(192*768+255)/256, 256, 0, stream>>>(fc1_w,  fc1W, 192, 768);
  wconv_kernel<<<(768*192+255)/256, 256, 0, stream>>>(fc2_w,  fc2W, 768, 192);
  btbl_kernel<<<(4*6*64*64+255)/256, 256, 0, stream>>>(rpb, btbl);

  // ---- phase 1: attention path, per batch image ----
  for (int b=0;b<4;b++){
    const float* xb = x   + (size_t)b*MB*CDIM;
    float*      ob  = out + (size_t)b*MB*CDIM;
    ln_kernel<true><<<MB/4, 256, 0, stream>>>(xb, n1g, n1b, Abuf);
    mgemm<EPI_QKV, 192, 576>
        <<<dim3(9, MB/128), 256, 0, stream>>>(Abuf, qkvW, qkv_b, (void*)Bq, nullptr);
    attn_kernel<<<WINB*6, 64, 0, stream>>>(Bq, btbl, Abuf);
    mgemm<EPI_PROJ, 192, 192>
        <<<dim3(3, MB/128), 256, 0, stream>>>(Abuf, prjW, proj_b, (void*)ob, xb);
  }
  // ---- phase 2: MLP path, per batch image ----
  for (int b=0;b<4;b++){
    float* ob = out + (size_t)b*MB*CDIM;
    ln_kernel<false><<<MB/4, 256, 0, stream>>>(ob, n2g, n2b, Abuf);
    mgemm<EPI_FC1, 192, 768>
        <<<dim3(12, MB/128), 256, 0, stream>>>(Abuf, fc1W, fc1_b, (void*)Bq, nullptr);
    mgemm<EPI_FC2, 768, 192>
        <<<dim3(3, MB/128), 256, 0, stream>>>(Bq, fc2W, fc2_b, (void*)ob, ob);
  }
}

// Round 5
// 798.265 us; speedup vs baseline: 3.7970x; 1.0460x over previous
//
#include <hip/hip_runtime.h>
#include <stdint.h>

// ---- problem constants (B=4, H=W=224, C=192, heads=6, win=7, shift=3) ----
#define MB    50176         // tokens per batch image (224*224)
#define CDIM  192

typedef __attribute__((ext_vector_type(8))) short bf16x8;   // MFMA A/B frag (4 VGPR)
typedef __attribute__((ext_vector_type(4))) float f32x4;    // MFMA C/D frag

__device__ __forceinline__ float wsum(float v){
  #pragma unroll
  for (int m=32;m>=1;m>>=1) v += __shfl_xor(v,m,64);
  return v;
}
__device__ __forceinline__ float bfbits2f(uint32_t h){
  union{uint32_t u; float f;} x; x.u = h<<16; return x.f;
}
__device__ __forceinline__ uint16_t f2bfbits(float f){
  union{float ff; uint32_t u;} x; x.ff = f;
  return (uint16_t)((x.u + 0x7FFFu + ((x.u>>16)&1u)) >> 16);
}
__device__ __forceinline__ void gload16(const void* g, void* l){
  __builtin_amdgcn_global_load_lds(
      (const __attribute__((address_space(1))) uint32_t*)g,
      (__attribute__((address_space(3))) uint32_t*)l, 16, 0, 0);
}
// window-order global row -> global token index (roll-back + window-reverse)
__device__ __forceinline__ size_t row2tok(int r_g){
  int widx = r_g/49, tpos = r_g - widx*49;
  int b = widx>>10, rem = widx&1023;
  int h = (rem>>5)*7 + tpos/7 + 3; if (h>=224) h-=224;
  int w = (rem&31)*7 + (tpos - (tpos/7)*7) + 3; if (w>=224) w-=224;
  return (size_t)b*MB + (size_t)h*224 + w;
}

// ---------------- prep: all weight converts (f32 KxN -> bf16 NxK) + btbl ---
__global__ __launch_bounds__(256) void prep_kernel(
    const float* __restrict__ qkv_w, const float* __restrict__ proj_w,
    const float* __restrict__ fc1_w, const float* __restrict__ fc2_w,
    const float* __restrict__ rpb,
    uint16_t* __restrict__ qkvW, uint16_t* __restrict__ prjW,
    uint16_t* __restrict__ fc1W, uint16_t* __restrict__ fc2W,
    float* __restrict__ btbl){
  int idx = blockIdx.x*256 + threadIdx.x;
  if (idx < 110592){ int k=idx/576, n=idx-k*576; qkvW[n*192+k]=f2bfbits(qkv_w[idx]); return; }
  idx -= 110592;
  if (idx < 36864){ int k=idx/192, n=idx-k*192; prjW[n*192+k]=f2bfbits(proj_w[idx]); return; }
  idx -= 36864;
  if (idx < 147456){ int k=idx/768, n=idx-k*768; fc1W[n*192+k]=f2bfbits(fc1_w[idx]); return; }
  idx -= 147456;
  if (idx < 147456){ int k=idx/192, n=idx-k*192; fc2W[n*768+k]=f2bfbits(fc2_w[idx]); return; }
  idx -= 147456;
  if (idx >= 98304) return;
  int j = idx & 63, i = (idx>>6) & 63;
  int hd = (idx>>12) % 6, cls = (idx>>12)/6;
  float v = -1e9f;
  if (i < 49 && j < 49){
    int dh = i/7 - j/7, dw = i%7 - j%7;
    v = rpb[((dh+6)*13 + (dw+6))*6 + hd];
    int cH = cls>>1, cW = cls&1;
    int li = (cH ? (i/7 < 4 ? 1 : 2) : 0)*3 + (cW ? (i%7 < 4 ? 1 : 2) : 0);
    int lj = (cH ? (j/7 < 4 ? 1 : 2) : 0)*3 + (cW ? (j%7 < 4 ? 1 : 2) : 0);
    if (li != lj) v = -1e9f;
  }
  btbl[idx] = v;
}

// ---------------- LN1 + roll + window-partition gather -> bf16 -------------
__global__ __launch_bounds__(256) void ln1_kernel(
    const float* __restrict__ x, const float* __restrict__ g,
    const float* __restrict__ bt, uint16_t* __restrict__ dst, int row0){
  int wid_l = (int)((blockIdx.x*256u + threadIdx.x) >> 6);
  int lane  = threadIdx.x & 63;
  size_t sidx = row2tok(row0 + wid_l);
  const float* s = x + sidx*CDIM;
  float v0=s[lane], v1=s[lane+64], v2=s[lane+128];
  float mu  = wsum(v0+v1+v2) * (1.f/192.f);
  float var = wsum(v0*v0+v1*v1+v2*v2)*(1.f/192.f) - mu*mu;
  float rs  = rsqrtf(var + 1e-5f);
  uint16_t* d = dst + (size_t)wid_l*CDIM;
  d[lane]     = f2bfbits((v0-mu)*rs*g[lane]     + bt[lane]);
  d[lane+64]  = f2bfbits((v1-mu)*rs*g[lane+64]  + bt[lane+64]);
  d[lane+128] = f2bfbits((v2-mu)*rs*g[lane+128] + bt[lane+128]);
}

// ---------------- MFMA GEMM: A bf16 [M][K], WT bf16 [N][K], 128x64 tile ----
enum { EPI_QKV=0, EPI_FC1=2, EPI_FC2=3 };

template<int EPI, int K, int NN>
__global__ __launch_bounds__(256) void mgemm(
    const uint16_t* __restrict__ A, const uint16_t* __restrict__ WT,
    const float* __restrict__ bias, void* __restrict__ outp,
    const float* __restrict__ resid, int row0){
  __shared__ __attribute__((aligned(16))) char As[128*128];
  __shared__ __attribute__((aligned(16))) char Bs[64*128];
  const int tid  = threadIdx.x;
  const int lane = tid & 63;
  const int wid  = tid >> 6;
  const int brow = blockIdx.y * 128;
  const int bcol = blockIdx.x * 64;

  f32x4 acc[4][2];
  #pragma unroll
  for (int m=0;m<4;m++)
    #pragma unroll
    for (int n=0;n<2;n++) acc[m][n] = (f32x4){0.f,0.f,0.f,0.f};

  const int srow = lane >> 3;
  const int sg   = (lane & 7) ^ srow;
  const int wm = wid >> 1, wn = wid & 1;
  const int lrow16 = lane & 15, lkh = lane >> 4;

  for (int k0 = 0; k0 < K; k0 += 64){
    #pragma unroll
    for (int c = 0; c < 4; c++){
      int ch = wid*4 + c;
      gload16(A + (size_t)(brow + ch*8 + srow)*K + k0 + sg*8, As + ch*1024);
    }
    #pragma unroll
    for (int c = 0; c < 2; c++){
      int ch = wid*2 + c;
      gload16(WT + (size_t)(bcol + ch*8 + srow)*K + k0 + sg*8, Bs + ch*1024);
    }
    __syncthreads();

    bf16x8 af[4][2], bfr[2][2];
    #pragma unroll
    for (int m=0;m<4;m++)
      #pragma unroll
      for (int ks=0;ks<2;ks++){
        int arow = wm*64 + m*16 + lrow16;
        af[m][ks] = *(const bf16x8*)(As + arow*128 + (((ks*4+lkh) ^ (arow&7))<<4));
      }
    #pragma unroll
    for (int n=0;n<2;n++)
      #pragma unroll
      for (int ks=0;ks<2;ks++){
        int brn = wn*32 + n*16 + lrow16;
        bfr[n][ks] = *(const bf16x8*)(Bs + brn*128 + (((ks*4+lkh) ^ (brn&7))<<4));
      }
    #pragma unroll
    for (int m=0;m<4;m++)
      #pragma unroll
      for (int n=0;n<2;n++)
        #pragma unroll
        for (int ks=0;ks<2;ks++)
          acc[m][n] = __builtin_amdgcn_mfma_f32_16x16x32_bf16(
              af[m][ks], bfr[n][ks], acc[m][n], 0, 0, 0);
    __syncthreads();
  }

  float bi[2];
  #pragma unroll
  for (int n=0;n<2;n++) bi[n] = bias[bcol + wn*32 + n*16 + lrow16];
  #pragma unroll
  for (int m=0;m<4;m++){
    #pragma unroll
    for (int j=0;j<4;j++){
      int r = brow + wm*64 + m*16 + lkh*4 + j;
      if constexpr (EPI==EPI_QKV || EPI==EPI_FC1){
        #pragma unroll
        for (int n=0;n<2;n++){
          float v = acc[m][n][j] + bi[n];
          if constexpr (EPI==EPI_FC1)
            v = 0.5f*v*(1.f + erff(v*0.70710678118654752f));  // exact gelu
          ((uint16_t*)outp)[(size_t)r*NN + bcol + wn*32 + n*16 + lrow16] = f2bfbits(v);
        }
      } else { // EPI_FC2: token scatter + residual(x2)
        size_t pr = row2tok(row0 + r)*CDIM;
        #pragma unroll
        for (int n=0;n<2;n++){
          size_t p = pr + bcol + wn*32 + n*16 + lrow16;
          ((float*)outp)[p] = acc[m][n][j] + bi[n] + resid[p];
        }
      }
    }
  }
}

// ---------------- proj GEMM (128x192 tile, 6 waves) + fused LN2 ------------
// A = attnout bf16 (window order). Writes x2 (f32, token order, = proj+bias+x)
// to xout and LN2(x2) bf16 IN-PLACE into ln2out (window order, block-local).
__global__ __launch_bounds__(384) void proj_ln2(
    const uint16_t* __restrict__ A, const uint16_t* __restrict__ WT,
    const float* __restrict__ pbias, const float* __restrict__ x,
    const float* __restrict__ g2, const float* __restrict__ b2,
    float* __restrict__ xout, uint16_t* __restrict__ ln2out, int row0){
  __shared__ __attribute__((aligned(16))) char As[128*128];   // [128][64k]
  __shared__ __attribute__((aligned(16))) char Bs[192*128];   // [192][64k]
  __shared__ float stats[3][128][2];
  const int tid  = threadIdx.x;
  const int lane = tid & 63;
  const int wid  = tid >> 6;          // 0..5
  const int wm = wid >> 2, wn3 = wid & 3; // (careful: want 2x3)
  // remap to 2 row-panels x 3 col-panels
  const int pm = wid / 3, pn = wid - pm*3;
  const int brow = blockIdx.x * 128;
  const int srow = lane >> 3;
  const int sg   = (lane & 7) ^ srow;
  const int lrow16 = lane & 15, lkh = lane >> 4;
  (void)wm; (void)wn3;

  f32x4 acc[4][4];
  #pragma unroll
  for (int m=0;m<4;m++)
    #pragma unroll
    for (int n=0;n<4;n++) acc[m][n] = (f32x4){0.f,0.f,0.f,0.f};

  for (int k0 = 0; k0 < 192; k0 += 64){
    for (int ch = wid; ch < 16; ch += 6)
      gload16(A + (size_t)(brow + ch*8 + srow)*192 + k0 + sg*8, As + ch*1024);
    for (int ch = wid; ch < 24; ch += 6)
      gload16(WT + (size_t)(ch*8 + srow)*192 + k0 + sg*8, Bs + ch*1024);
    __syncthreads();

    bf16x8 af[4][2], bfr[4][2];
    #pragma unroll
    for (int m=0;m<4;m++)
      #pragma unroll
      for (int ks=0;ks<2;ks++){
        int arow = pm*64 + m*16 + lrow16;
        af[m][ks] = *(const bf16x8*)(As + arow*128 + (((ks*4+lkh) ^ (arow&7))<<4));
      }
    #pragma unroll
    for (int n=0;n<4;n++)
      #pragma unroll
      for (int ks=0;ks<2;ks++){
        int brn = pn*64 + n*16 + lrow16;
        bfr[n][ks] = *(const bf16x8*)(Bs + brn*128 + (((ks*4+lkh) ^ (brn&7))<<4));
      }
    #pragma unroll
    for (int m=0;m<4;m++)
      #pragma unroll
      for (int n=0;n<4;n++)
        #pragma unroll
        for (int ks=0;ks<2;ks++)
          acc[m][n] = __builtin_amdgcn_mfma_f32_16x16x32_bf16(
              af[m][ks], bfr[n][ks], acc[m][n], 0, 0, 0);
    __syncthreads();
  }

  float bi[4], g2v[4], b2v[4];
  #pragma unroll
  for (int n=0;n<4;n++){
    int c = pn*64 + n*16 + lrow16;
    bi[n] = pbias[c]; g2v[n] = g2[c]; b2v[n] = b2[c];
  }
  // pass 1: y = acc + bias + x[token]; write x2; row partial sums
  #pragma unroll
  for (int m=0;m<4;m++){
    #pragma unroll
    for (int j=0;j<4;j++){
      int r = pm*64 + m*16 + lkh*4 + j;            // local row in [0,128)
      size_t pr = row2tok(row0 + brow + r)*CDIM;
      float s1 = 0.f, s2 = 0.f;
      #pragma unroll
      for (int n=0;n<4;n++){
        int c = pn*64 + n*16 + lrow16;
        float y = acc[m][n][j] + bi[n] + x[pr + c];
        acc[m][n][j] = y;
        xout[pr + c] = y;
        s1 += y; s2 = fmaf(y, y, s2);
      }
      #pragma unroll
      for (int mk=1; mk<16; mk<<=1){
        s1 += __shfl_xor(s1, mk, 64);
        s2 += __shfl_xor(s2, mk, 64);
      }
      if (lrow16 == 0){ stats[pn][r][0] = s1; stats[pn][r][1] = s2; }
    }
  }
  __syncthreads();
  // pass 2: normalize, write ln2out (window order, in-place over A rows)
  #pragma unroll
  for (int m=0;m<4;m++){
    #pragma unroll
    for (int j=0;j<4;j++){
      int r = pm*64 + m*16 + lkh*4 + j;
      float s1 = stats[0][r][0] + stats[1][r][0] + stats[2][r][0];
      float s2 = stats[0][r][1] + stats[1][r][1] + stats[2][r][1];
      float mu = s1*(1.f/192.f);
      float rs = rsqrtf(s2*(1.f/192.f) - mu*mu + 1e-5f);
      size_t pr = (size_t)(brow + r)*CDIM;
      #pragma unroll
      for (int n=0;n<4;n++){
        int c = pn*64 + n*16 + lrow16;
        ln2out[pr + c] = f2bfbits((acc[m][n][j]-mu)*rs*g2v[n] + b2v[n]);
      }
    }
  }
}

// ---------------- MFMA windowed attention: one WAVE per (window, head) -----
__global__ __launch_bounds__(64) void attn_kernel(
    const uint16_t* __restrict__ qkv, const float* __restrict__ btbl,
    uint16_t* __restrict__ attnout, int win0){
  const int bid  = blockIdx.x;
  const int widx = bid/6, hd = bid - widx*6;     // local window idx
  const int lane = threadIdx.x;
  const int r16 = lane & 15, t4 = lane >> 4;
  __shared__ uint16_t Vt[32][72];     // V^T  (stride 144B: 2-way = free)
  __shared__ uint16_t Pl[16][72];     // one P i-tile (reused; same-wave FIFO)

  #pragma unroll
  for (int e=lane; e<32*16; e+=64){ Vt[e>>4][48 + (e&15)] = 0; }
  for (int ch = lane; ch < 196; ch += 64){
    int j = ch >> 2, c0 = (ch&3)*8;
    const uint16_t* src = qkv + ((size_t)widx*49 + j)*576 + hd*32 + 384 + c0;
    uint4 v = *(const uint4*)src;
    uint32_t u[4] = {v.x, v.y, v.z, v.w};
    #pragma unroll
    for (int q=0;q<8;q++) Vt[c0+q][j] = (uint16_t)(u[q>>1] >> ((q&1)*16));
  }

  // QK^T (swapped): acc[jt][it] -> S[i = it*16+r16][j = jt*16+t4*4+r]
  bf16x8 kf[4], qf[4];
  #pragma unroll
  for (int jt=0;jt<4;jt++)
    kf[jt] = *(const bf16x8*)(qkv + ((size_t)widx*49 + jt*16 + r16)*576 + hd*32 + 192 + t4*8);
  #pragma unroll
  for (int it=0;it<4;it++)
    qf[it] = *(const bf16x8*)(qkv + ((size_t)widx*49 + it*16 + r16)*576 + hd*32 + t4*8);
  f32x4 acc[4][4];
  #pragma unroll
  for (int jt=0;jt<4;jt++)
    #pragma unroll
    for (int it=0;it<4;it++){
      acc[jt][it] = (f32x4){0.f,0.f,0.f,0.f};
      acc[jt][it] = __builtin_amdgcn_mfma_f32_16x16x32_bf16(kf[jt], qf[it], acc[jt][it], 0,0,0);
    }
  __syncthreads();    // Vt ready (single wave: just a waitcnt)

  const int gw = win0 + widx;
  const int cls = ((((gw&1023)>>5)==31)<<1) | ((gw&31)==31);
  const float* tb = btbl + ((size_t)(cls*6 + hd) << 12);
  const float scale = 0.17677669529663689f;

  bf16x8 bv[2][2];
  #pragma unroll
  for (int ct=0;ct<2;ct++)
    #pragma unroll
    for (int ks=0;ks<2;ks++)
      bv[ct][ks] = *(const bf16x8*)&Vt[ct*16 + r16][ks*32 + t4*8];

  #pragma unroll
  for (int it=0;it<4;it++){
    int i = it*16 + r16;
    float s[4][4];
    float m = -3.4e38f;
    #pragma unroll
    for (int jt=0;jt<4;jt++){
      float4 bvv = *(const float4*)(tb + i*64 + jt*16 + t4*4);
      float bb[4] = {bvv.x, bvv.y, bvv.z, bvv.w};
      #pragma unroll
      for (int r=0;r<4;r++){
        s[jt][r] = acc[jt][it][r]*scale + bb[r];
        m = fmaxf(m, s[jt][r]);
      }
    }
    m = fmaxf(m, __shfl_xor(m, 16, 64));
    m = fmaxf(m, __shfl_xor(m, 32, 64));
    float sum = 0.f;
    #pragma unroll
    for (int jt=0;jt<4;jt++)
      #pragma unroll
      for (int r=0;r<4;r++){
        s[jt][r] = __expf(s[jt][r] - m);
        sum += s[jt][r];
      }
    sum += __shfl_xor(sum, 16, 64);
    sum += __shfl_xor(sum, 32, 64);
    float inv = 1.f / sum;
    #pragma unroll
    for (int jt=0;jt<4;jt++){
      uint32_t lo = (uint32_t)f2bfbits(s[jt][0]*inv) | ((uint32_t)f2bfbits(s[jt][1]*inv) << 16);
      uint32_t hi = (uint32_t)f2bfbits(s[jt][2]*inv) | ((uint32_t)f2bfbits(s[jt][3]*inv) << 16);
      *(uint2*)&Pl[r16][jt*16 + t4*4] = make_uint2(lo, hi);
    }
    __syncthreads();   // same-wave LDS fence

    f32x4 o[2];
    o[0] = (f32x4){0.f,0.f,0.f,0.f};
    o[1] = (f32x4){0.f,0.f,0.f,0.f};
    #pragma unroll
    for (int ks=0;ks<2;ks++){
      bf16x8 pa = *(const bf16x8*)&Pl[r16][ks*32 + t4*8];
      #pragma unroll
      for (int ct=0;ct<2;ct++)
        o[ct] = __builtin_amdgcn_mfma_f32_16x16x32_bf16(pa, bv[ct][ks], o[ct], 0,0,0);
    }
    #pragma unroll
    for (int r=0;r<4;r++){
      int i2 = it*16 + t4*4 + r;
      if (i2 < 49){
        size_t base = ((size_t)widx*49 + i2)*CDIM + hd*32;
        attnout[base + r16]      = f2bfbits(o[0][r]);
        attnout[base + 16 + r16] = f2bfbits(o[1][r]);
      }
    }
  }
}

// ---------------------------------------------------------------------------
extern "C" void kernel_launch(void* const* d_in, const int* in_sizes, int n_in,
                              void* d_out, int out_size, void* d_ws, size_t ws_size,
                              hipStream_t stream) {
  const float* x       = (const float*)d_in[0];
  const float* n1g     = (const float*)d_in[1];
  const float* n1b     = (const float*)d_in[2];
  const float* qkv_w   = (const float*)d_in[3];
  const float* qkv_b   = (const float*)d_in[4];
  const float* rpb     = (const float*)d_in[5];
  const float* proj_w  = (const float*)d_in[6];
  const float* proj_b  = (const float*)d_in[7];
  const float* n2g     = (const float*)d_in[8];
  const float* n2b     = (const float*)d_in[9];
  const float* fc1_w   = (const float*)d_in[10];
  const float* fc1_b   = (const float*)d_in[11];
  const float* fc2_w   = (const float*)d_in[12];
  const float* fc2_b   = (const float*)d_in[13];
  float* out = (float*)d_out;

  // full-batch mode if ws allows: Abuf T*192*2 + Bq T*768*2 + tables 1.28MB
  const size_t TBL = 221184 + 73728 + 294912 + 294912 + 393216;
  size_t need_full = (size_t)200704*CDIM*2 + (size_t)200704*768*2 + TBL;
  bool full = ws_size >= need_full;
  int T  = full ? 200704 : MB;       // rows per chunk
  int NC = full ? 1 : 4;
  int NW = T / 49;                   // windows per chunk

  char* ws = (char*)d_ws;
  uint16_t* Abuf = (uint16_t*)ws;
  uint16_t* Bq   = (uint16_t*)(ws + (size_t)T*CDIM*2);
  char* wbase    = ws + (size_t)T*CDIM*2 + (size_t)T*768*2;
  uint16_t* qkvW = (uint16_t*)wbase;
  uint16_t* prjW = (uint16_t*)(wbase + 221184);
  uint16_t* fc1W = (uint16_t*)(wbase + 221184 + 73728);
  uint16_t* fc2W = (uint16_t*)(wbase + 221184 + 73728 + 294912);
  float*    btbl = (float*)(wbase + 221184 + 73728 + 294912 + 294912);

  prep_kernel<<<2112, 256, 0, stream>>>(qkv_w, proj_w, fc1_w, fc2_w, rpb,
                                        qkvW, prjW, fc1W, fc2W, btbl);

  for (int c = 0; c < NC; c++){
    int row0 = c*T, win0 = row0/49;
    ln1_kernel<<<T/4, 256, 0, stream>>>(x, n1g, n1b, Abuf, row0);
    mgemm<EPI_QKV, 192, 576>
        <<<dim3(9, T/128), 256, 0, stream>>>(Abuf, qkvW, qkv_b, (void*)Bq, nullptr, 0);
    attn_kernel<<<NW*6, 64, 0, stream>>>(Bq, btbl, Abuf, win0);
    proj_ln2<<<T/128, 384, 0, stream>>>(Abuf, prjW, proj_b, x, n2g, n2b,
                                        out, Abuf, row0);
    mgemm<EPI_FC1, 192, 768>
        <<<dim3(12, T/128), 256, 0, stream>>>(Abuf, fc1W, fc1_b, (void*)Bq, nullptr, 0);
    mgemm<EPI_FC2, 768, 192>
        <<<dim3(3, T/128), 256, 0, stream>>>(Bq, fc2W, fc2_b, (void*)out, out, row0);
  }
}